// Round 2
// baseline (607.251 us; speedup 1.0000x reference)
//
#include <hip/hip_runtime.h>

#define V 32000
#define E 1024
#define H 1024
#define B 64
#define T 512

// ---------------- attention: u2[k] = sum_h v[h] * W[h, H+k] ----------------
__global__ void u2_kernel(const float* __restrict__ W, const float* __restrict__ v,
                          float* __restrict__ u2) {
    int k = blockIdx.x * 256 + threadIdx.x;   // 0..1023
    float acc = 0.f;
#pragma unroll 4
    for (int h = 0; h < H; ++h) acc += v[h] * W[h * 2048 + 1024 + k];
    u2[k] = acc;
}

// scores[b,t] = enc[t,b,:] . u2  (per-b constant part of the score cancels in softmax)
__global__ void scores_kernel(const float4* __restrict__ enc, const float4* __restrict__ u2,
                              float* __restrict__ scores) {
    int wid = (blockIdx.x * blockDim.x + threadIdx.x) >> 6;
    int lane = threadIdx.x & 63;
    int b = wid >> 9;       // / T
    int t = wid & 511;      // % T
    const float4* p = enc + (size_t)(t * B + b) * (H / 4);
    float acc = 0.f;
#pragma unroll
    for (int i = 0; i < 4; ++i) {
        float4 a = p[lane + 64 * i];
        float4 u = u2[lane + 64 * i];
        acc += a.x * u.x + a.y * u.y + a.z * u.z + a.w * u.w;
    }
#pragma unroll
    for (int off = 32; off; off >>= 1) acc += __shfl_xor(acc, off);
    if (lane == 0) scores[b * T + t] = acc;
}

__global__ void softmax_kernel(const float* __restrict__ scores, float* __restrict__ attn_ws,
                               float* __restrict__ attn_out) {
    int b = blockIdx.x;
    int tid = threadIdx.x;  // 256
    int wid = tid >> 6, lane = tid & 63;
    float s0 = scores[b * T + tid];
    float s1 = scores[b * T + tid + 256];
    float m = fmaxf(s0, s1);
    __shared__ float red[4], red2[4];
#pragma unroll
    for (int off = 32; off; off >>= 1) m = fmaxf(m, __shfl_xor(m, off));
    if (lane == 0) red[wid] = m;
    __syncthreads();
    float mb = fmaxf(fmaxf(red[0], red[1]), fmaxf(red[2], red[3]));
    float e0 = expf(s0 - mb), e1 = expf(s1 - mb);
    float s = e0 + e1;
#pragma unroll
    for (int off = 32; off; off >>= 1) s += __shfl_xor(s, off);
    if (lane == 0) red2[wid] = s;
    __syncthreads();
    float inv = 1.f / (red2[0] + red2[1] + red2[2] + red2[3]);
    attn_ws[b * T + tid] = e0 * inv;
    attn_ws[b * T + tid + 256] = e1 * inv;
    attn_out[b * T + tid] = e0 * inv;
    attn_out[b * T + tid + 256] = e1 * inv;
}

// context partial sums: part[tc][b][h] = sum_{t in chunk} attn[b,t]*enc[t,b,h]
__global__ void ctx_partial(const float* __restrict__ attn, const float* __restrict__ enc,
                            float* __restrict__ part) {
    int hc = blockIdx.x;   // 0..3
    int b  = blockIdx.y;   // 0..63
    int tc = blockIdx.z;   // 0..3
    int h = hc * 256 + threadIdx.x;
    int tbase = tc * 128;
    float acc0 = 0.f, acc1 = 0.f;
    for (int t = 0; t < 128; t += 2) {
        acc0 += attn[b * T + tbase + t]     * enc[((size_t)(tbase + t) * B + b) * H + h];
        acc1 += attn[b * T + tbase + t + 1] * enc[((size_t)(tbase + t + 1) * B + b) * H + h];
    }
    part[((size_t)tc * B + b) * H + h] = acc0 + acc1;
}

// reduce partials -> xT lower half in [K/4][B][4] layout (float idx == linear idx)
__global__ void ctx_reduce(const float* __restrict__ part, float* __restrict__ xT) {
    int idx = blockIdx.x * 256 + threadIdx.x;   // 0..65535
    int k = ((idx >> 8) << 2) | (idx & 3);
    int b = (idx >> 2) & 63;
    float s = part[(0 * B + b) * H + k] + part[(1 * B + b) * H + k] +
              part[(2 * B + b) * H + k] + part[(3 * B + b) * H + k];
    xT[idx] = s;
}

__global__ void embT_kernel(const int* __restrict__ tok, const float* __restrict__ emb,
                            float* __restrict__ xT_hi) {
    int idx = blockIdx.x * 256 + threadIdx.x;   // 0..65535
    int e = ((idx >> 8) << 2) | (idx & 3);
    int b = (idx >> 2) & 63;
    xT_hi[idx] = emb[(size_t)tok[b] * E + e];
}

__global__ void h0T_kernel(const float* __restrict__ h0, float* __restrict__ h0T) {
    int idx = blockIdx.x * 256 + threadIdx.x;   // 0..131071 (both layers)
    int l = idx >> 16;
    int r = idx & 65535;
    int k = ((r >> 8) << 2) | (r & 3);
    int b = (r >> 2) & 63;
    h0T[idx] = h0[l * 65536 + b * 1024 + k];
}

// GEMM: out[j,b] (or out[b,j]) = sum_k AT4[k4*64+b][c] * W[j,k] (+bias)
// A in [K/4][B][4] float4 layout. grid.y picks between two independent problems.
template <bool OUT_BT>
__global__ __launch_bounds__(256) void gemm_tn(
    const float4* __restrict__ A0, const float* __restrict__ W0, int K0,
    const float* __restrict__ ba0, const float* __restrict__ bb0, float* __restrict__ out0,
    const float4* __restrict__ A1, const float* __restrict__ W1, int K1,
    float* __restrict__ out1, int ldo) {
    const float4* A; const float* W; const float* ba; const float* bb; float* out; int K;
    if (blockIdx.y == 0) { A = A0; W = W0; K = K0; ba = ba0; bb = bb0; out = out0; }
    else                 { A = A1; W = W1; K = K1; ba = nullptr; bb = nullptr; out = out1; }
    int lane = threadIdx.x & 63;
    int wid = __builtin_amdgcn_readfirstlane(threadIdx.x >> 6);
    int j0 = blockIdx.x * 16 + wid * 4;
    float acc[4] = {0.f, 0.f, 0.f, 0.f};
    __shared__ float4 smem[2048];   // 128 k x 64 b, 32KB
    for (int k0 = 0; k0 < K; k0 += 128) {
        __syncthreads();
        const float4* src = A + (k0 >> 2) * 64;
#pragma unroll
        for (int i = 0; i < 8; ++i) smem[threadIdx.x + i * 256] = src[threadIdx.x + i * 256];
        __syncthreads();
#pragma unroll 4
        for (int k4 = 0; k4 < 32; ++k4) {
            float4 a = smem[k4 * 64 + lane];
#pragma unroll
            for (int jj = 0; jj < 4; ++jj) {
                const float4 w =
                    *reinterpret_cast<const float4*>(W + (size_t)(j0 + jj) * K + k0 + k4 * 4);
                acc[jj] += a.x * w.x + a.y * w.y + a.z * w.z + a.w * w.w;
            }
        }
    }
    if (OUT_BT) {
#pragma unroll
        for (int jj = 0; jj < 4; ++jj) {
            float bv = (ba ? ba[j0 + jj] : 0.f) + (bb ? bb[j0 + jj] : 0.f);
            out[(size_t)(j0 + jj) * 64 + lane] = acc[jj] + bv;
        }
    } else {
        float4 r;
        if (ba) {
            const float4 bv = *reinterpret_cast<const float4*>(ba + j0);
            r.x = acc[0] + bv.x; r.y = acc[1] + bv.y; r.z = acc[2] + bv.z; r.w = acc[3] + bv.w;
        } else {
            r.x = acc[0]; r.y = acc[1]; r.z = acc[2]; r.w = acc[3];
        }
        *reinterpret_cast<float4*>(out + (size_t)lane * ldo + j0) = r;
    }
}

__global__ void lstm_elem(const float* __restrict__ gA, const float* __restrict__ gB,
                          const float* __restrict__ c_prev, float* __restrict__ h_out,
                          float* __restrict__ c_out, float* __restrict__ hT) {
    int idx = blockIdx.x * 256 + threadIdx.x;   // 0..65535
    int b = idx >> 10, k = idx & 1023;
    float gi = gA[(size_t)k * 64 + b]          + gB[(size_t)k * 64 + b];
    float gf = gA[(size_t)(1024 + k) * 64 + b] + gB[(size_t)(1024 + k) * 64 + b];
    float gg = gA[(size_t)(2048 + k) * 64 + b] + gB[(size_t)(2048 + k) * 64 + b];
    float go = gA[(size_t)(3072 + k) * 64 + b] + gB[(size_t)(3072 + k) * 64 + b];
    float i_ = 1.f / (1.f + expf(-gi));
    float f_ = 1.f / (1.f + expf(-gf));
    float g_ = tanhf(gg);
    float o_ = 1.f / (1.f + expf(-go));
    float c = f_ * c_prev[idx] + i_ * g_;
    float h = o_ * tanhf(c);
    c_out[idx] = c;
    h_out[idx] = h;
    hT[(k >> 2) * 256 + b * 4 + (k & 3)] = h;
}

// log-softmax over V per row, split into 4 chunks per row for parallelism
__global__ void lse_partial(const float* __restrict__ logits, float* __restrict__ pm,
                            float* __restrict__ ps) {
    int bi = blockIdx.x;   // 0..255
    int b = bi >> 2, c = bi & 3;
    int tid = threadIdx.x;
    const float* row = logits + (size_t)b * V + c * 8192;
    int lim = V - c * 8192;
    if (lim > 8192) lim = 8192;
    float m = -1e30f, s = 0.f;
    for (int i = 0; i < 32; ++i) {
        int v = i * 256 + tid;
        if (v < lim) {
            float x = row[v];
            if (x > m) { s = s * expf(m - x) + 1.f; m = x; }
            else s += expf(x - m);
        }
    }
#pragma unroll
    for (int off = 32; off; off >>= 1) {
        float m2 = __shfl_xor(m, off);
        float s2 = __shfl_xor(s, off);
        float mn = fmaxf(m, m2);
        s = s * expf(m - mn) + s2 * expf(m2 - mn);
        m = mn;
    }
    __shared__ float mred[4], sred[4];
    int wid = tid >> 6, lane = tid & 63;
    if (lane == 0) { mred[wid] = m; sred[wid] = s; }
    __syncthreads();
    if (tid == 0) {
        float M = mred[0], S = sred[0];
        for (int i = 1; i < 4; ++i) {
            float mn = fmaxf(M, mred[i]);
            S = S * expf(M - mn) + sred[i] * expf(mred[i] - mn);
            M = mn;
        }
        pm[bi] = M;
        ps[bi] = S;
    }
}

__global__ void lse_final(const float* __restrict__ pm, const float* __restrict__ ps,
                          float* __restrict__ lse) {
    int b = threadIdx.x;   // 64
    float M = pm[b * 4], S = ps[b * 4];
    for (int i = 1; i < 4; ++i) {
        float m2 = pm[b * 4 + i];
        float mn = fmaxf(M, m2);
        S = S * expf(M - mn) + ps[b * 4 + i] * expf(m2 - mn);
        M = mn;
    }
    lse[b] = M + logf(S);
}

__global__ void lse_sub(float* __restrict__ logits, const float* __restrict__ lse) {
    int b = blockIdx.y;
    int v = blockIdx.x * 256 + threadIdx.x;
    logits[(size_t)b * V + v] -= lse[b];
}

extern "C" void kernel_launch(void* const* d_in, const int* in_sizes, int n_in,
                              void* d_out, int out_size, void* d_ws, size_t ws_size,
                              hipStream_t stream) {
    const int*   tok   = (const int*)d_in[0];
    const float* h0    = (const float*)d_in[1];
    const float* c0    = (const float*)d_in[2];
    const float* enc   = (const float*)d_in[3];
    const float* emb   = (const float*)d_in[4];
    const float* attnW = (const float*)d_in[5];
    // d_in[6] attn_b: its contribution to scores is constant over t -> cancels in softmax
    const float* attnv = (const float*)d_in[7];
    const float* w_ih0 = (const float*)d_in[8];
    const float* w_hh0 = (const float*)d_in[9];
    const float* b_ih0 = (const float*)d_in[10];
    const float* b_hh0 = (const float*)d_in[11];
    const float* w_ih1 = (const float*)d_in[12];
    const float* w_hh1 = (const float*)d_in[13];
    const float* b_ih1 = (const float*)d_in[14];
    const float* b_hh1 = (const float*)d_in[15];
    const float* out_W = (const float*)d_in[16];
    const float* out_b = (const float*)d_in[17];
    float* out = (float*)d_out;
    float* ws = (float*)d_ws;

    float* u2     = ws + 0;        // 1024
    float* scores = ws + 1024;     // 32768
    float* attn   = ws + 33792;    // 32768
    float* part   = ws + 66560;    // 262144 (reused as gA)
    float* xT     = ws + 328704;   // 131072  [2048/4][64][4]
    float* h0T    = ws + 459776;   // 131072  two layers
    float* gB     = ws + 590848;   // 262144
    float* h1T    = ws + 852992;   // 65536
    float* h2T    = ws + 918528;   // 65536
    float* pm     = ws + 984064;   // 256
    float* ps     = ws + 984320;   // 256
    float* lsebuf = ws + 984576;   // 64
    float* gA = part;

    float* out_logits = out;                 // [64][32000]
    float* out_h1 = out + 2048000;
    float* out_h2 = out + 2113536;
    float* out_c1 = out + 2179072;
    float* out_c2 = out + 2244608;
    float* out_attn = out + 2310144;         // [64][1][512]

    u2_kernel<<<4, 256, 0, stream>>>(attnW, attnv, u2);
    scores_kernel<<<8192, 256, 0, stream>>>((const float4*)enc, (const float4*)u2, scores);
    softmax_kernel<<<64, 256, 0, stream>>>(scores, attn, out_attn);
    ctx_partial<<<dim3(4, 64, 4), 256, 0, stream>>>(attn, enc, part);
    ctx_reduce<<<256, 256, 0, stream>>>(part, xT);
    embT_kernel<<<256, 256, 0, stream>>>(tok, emb, xT + 65536);
    h0T_kernel<<<512, 256, 0, stream>>>(h0, h0T);

    // layer 0 gates: gA = xT(K=2048) . w_ih0^T + biases ; gB = h0T[0](K=1024) . w_hh0^T
    gemm_tn<true><<<dim3(256, 2), 256, 0, stream>>>(
        (const float4*)xT, w_ih0, 2048, b_ih0, b_hh0, gA,
        (const float4*)h0T, w_hh0, 1024, gB, 0);
    lstm_elem<<<256, 256, 0, stream>>>(gA, gB, c0, out_h1, out_c1, h1T);

    // layer 1 gates
    gemm_tn<true><<<dim3(256, 2), 256, 0, stream>>>(
        (const float4*)h1T, w_ih1, 1024, b_ih1, b_hh1, gA,
        (const float4*)(h0T + 65536), w_hh1, 1024, gB, 0);
    lstm_elem<<<256, 256, 0, stream>>>(gA, gB, c0 + 65536, out_h2, out_c2, h2T);

    // logits = h2 . out_W^T + out_b  -> [64][32000] directly in d_out
    gemm_tn<false><<<dim3(2000, 1), 256, 0, stream>>>(
        (const float4*)h2T, out_W, 1024, out_b, nullptr, out_logits,
        nullptr, nullptr, 0, nullptr, V);

    lse_partial<<<256, 256, 0, stream>>>(out_logits, pm, ps);
    lse_final<<<1, 64, 0, stream>>>(pm, ps, lsebuf);
    lse_sub<<<dim3(125, 64), 256, 0, stream>>>(out_logits, lsebuf);
}

// Round 5
// 492.078 us; speedup vs baseline: 1.2341x; 1.2341x over previous
//
#include <hip/hip_runtime.h>

#define V 32000
#define E 1024
#define H 1024
#define B 64
#define T 512

// ---------- u2[k] = sum_h v[h] * W[h, H+k]  (32 h-chunk partials) ----------
__global__ void u2_partial(const float4* __restrict__ W4, const float* __restrict__ v,
                           float4* __restrict__ u2p) {
    int hc = blockIdx.x;           // 0..31
    int k4 = threadIdx.x;          // 0..255
    float4 acc = {0.f, 0.f, 0.f, 0.f};
#pragma unroll 4
    for (int i = 0; i < 32; ++i) {
        int h = hc * 32 + i;
        float vv = v[h];
        float4 w = W4[(size_t)h * 512 + 256 + k4];   // cols 1024..2047
        acc.x += vv * w.x; acc.y += vv * w.y; acc.z += vv * w.z; acc.w += vv * w.w;
    }
    u2p[hc * 256 + k4] = acc;
}

__global__ void u2_reduce(const float4* __restrict__ u2p, float4* __restrict__ u2) {
    int k4 = threadIdx.x;          // 0..255
    float4 acc = {0.f, 0.f, 0.f, 0.f};
#pragma unroll
    for (int hc = 0; hc < 32; ++hc) {
        float4 p = u2p[hc * 256 + k4];
        acc.x += p.x; acc.y += p.y; acc.z += p.z; acc.w += p.w;
    }
    u2[k4] = acc;
}

// scores[b,t] = enc[t,b,:] . u2  (per-b constant part cancels in softmax)
__global__ void scores_kernel(const float4* __restrict__ enc, const float4* __restrict__ u2,
                              float* __restrict__ scores) {
    int wid = (blockIdx.x * blockDim.x + threadIdx.x) >> 6;
    int lane = threadIdx.x & 63;
    int b = wid >> 9;
    int t = wid & 511;
    const float4* p = enc + (size_t)(t * B + b) * (H / 4);
    float acc = 0.f;
#pragma unroll
    for (int i = 0; i < 4; ++i) {
        float4 a = p[lane + 64 * i];
        float4 u = u2[lane + 64 * i];
        acc += a.x * u.x + a.y * u.y + a.z * u.z + a.w * u.w;
    }
#pragma unroll
    for (int off = 32; off; off >>= 1) acc += __shfl_xor(acc, off);
    if (lane == 0) scores[b * T + t] = acc;
}

__global__ void softmax_kernel(const float* __restrict__ scores, float* __restrict__ attn_ws,
                               float* __restrict__ attn_out) {
    int b = blockIdx.x;
    int tid = threadIdx.x;  // 256
    int wid = tid >> 6, lane = tid & 63;
    float s0 = scores[b * T + tid];
    float s1 = scores[b * T + tid + 256];
    float m = fmaxf(s0, s1);
    __shared__ float red[4], red2[4];
#pragma unroll
    for (int off = 32; off; off >>= 1) m = fmaxf(m, __shfl_xor(m, off));
    if (lane == 0) red[wid] = m;
    __syncthreads();
    float mb = fmaxf(fmaxf(red[0], red[1]), fmaxf(red[2], red[3]));
    float e0 = expf(s0 - mb), e1 = expf(s1 - mb);
    float s = e0 + e1;
#pragma unroll
    for (int off = 32; off; off >>= 1) s += __shfl_xor(s, off);
    if (lane == 0) red2[wid] = s;
    __syncthreads();
    float inv = 1.f / (red2[0] + red2[1] + red2[2] + red2[3]);
    attn_ws[b * T + tid] = e0 * inv;
    attn_ws[b * T + tid + 256] = e1 * inv;
    attn_out[b * T + tid] = e0 * inv;
    attn_out[b * T + tid + 256] = e1 * inv;
}

// context partials, written directly in xT ([h/4][b][4]) layout per t-chunk
__global__ void ctx_partial(const float* __restrict__ attn, const float4* __restrict__ enc4,
                            float4* __restrict__ part) {
    int b = blockIdx.x;      // 0..63
    int tc = blockIdx.y;     // 0..15
    int h4 = threadIdx.x;    // 0..255
    float4 acc = {0.f, 0.f, 0.f, 0.f};
#pragma unroll 4
    for (int t = 0; t < 32; ++t) {
        int tt = tc * 32 + t;
        float w = attn[b * T + tt];
        float4 e = enc4[((size_t)tt * B + b) * 256 + h4];
        acc.x += w * e.x; acc.y += w * e.y; acc.z += w * e.z; acc.w += w * e.w;
    }
    part[(size_t)tc * 16384 + h4 * 64 + b] = acc;
}

__global__ void ctx_reduce(const float4* __restrict__ part, float4* __restrict__ xT4) {
    int idx = blockIdx.x * 256 + threadIdx.x;   // 0..16383
    float4 acc = {0.f, 0.f, 0.f, 0.f};
#pragma unroll
    for (int tc = 0; tc < 16; ++tc) {
        float4 p = part[tc * 16384 + idx];
        acc.x += p.x; acc.y += p.y; acc.z += p.z; acc.w += p.w;
    }
    xT4[idx] = acc;
}

__global__ void embT_kernel(const int* __restrict__ tok, const float* __restrict__ emb,
                            float* __restrict__ xT_hi) {
    int idx = blockIdx.x * 256 + threadIdx.x;   // 0..65535
    int e = ((idx >> 8) << 2) | (idx & 3);
    int b = (idx >> 2) & 63;
    xT_hi[idx] = emb[(size_t)tok[b] * E + e];
}

__global__ void h0T_kernel(const float* __restrict__ h0, float* __restrict__ h0T) {
    int idx = blockIdx.x * 256 + threadIdx.x;   // 0..131071 (both layers)
    int l = idx >> 16;
    int r = idx & 65535;
    int k = ((r >> 8) << 2) | (r & 3);
    int b = (r >> 2) & 63;
    h0T[idx] = h0[l * 65536 + b * 1024 + k];
}

// ---------- streaming GEMM partials: 8 rows/wave, no LDS, no barriers ----------
struct GJob {
    const float4* A;    // [K/4][64] float4
    const float4* W4;   // row-major [N][K/4] float4
    float* out;         // [4096][64] partial
    int ldw4;           // K/4
    int k4_off;
    int k4_len;
};

__global__ __launch_bounds__(256) void gemm_gates(GJob j0, GJob j1, GJob j2, GJob j3) {
    GJob job;
    if (blockIdx.y == 0) job = j0;
    else if (blockIdx.y == 1) job = j1;
    else if (blockIdx.y == 2) job = j2;
    else job = j3;
    int lane = threadIdx.x & 63;
    int wid = __builtin_amdgcn_readfirstlane(threadIdx.x >> 6);
    int row0 = blockIdx.x * 32 + wid * 8;
    const float4* Ap = job.A + (size_t)job.k4_off * 64;
    const float4* Wp = job.W4 + (size_t)row0 * job.ldw4 + job.k4_off;
    float acc[8] = {0.f, 0.f, 0.f, 0.f, 0.f, 0.f, 0.f, 0.f};
#pragma unroll 2
    for (int k4 = 0; k4 < job.k4_len; ++k4) {
        float4 a = Ap[(size_t)k4 * 64 + lane];
#pragma unroll
        for (int r = 0; r < 8; ++r) {
            float4 w = Wp[(size_t)r * job.ldw4 + k4];
            acc[r] += a.x * w.x + a.y * w.y + a.z * w.z + a.w * w.w;
        }
    }
#pragma unroll
    for (int r = 0; r < 8; ++r) job.out[(size_t)(row0 + r) * 64 + lane] = acc[r];
}

// logits: out[b][j] = h2 . out_W[j] + bias[j], K=1024 fixed
__global__ __launch_bounds__(256) void gemm_logits(const float4* __restrict__ A,
                                                   const float4* __restrict__ W4,
                                                   const float* __restrict__ bias,
                                                   float* __restrict__ out) {
    int lane = threadIdx.x & 63;
    int wid = __builtin_amdgcn_readfirstlane(threadIdx.x >> 6);
    int row0 = blockIdx.x * 32 + wid * 8;   // grid.x = 1000
    const float4* Wp = W4 + (size_t)row0 * 256;
    float acc[8] = {0.f, 0.f, 0.f, 0.f, 0.f, 0.f, 0.f, 0.f};
#pragma unroll 2
    for (int k4 = 0; k4 < 256; ++k4) {
        float4 a = A[k4 * 64 + lane];
#pragma unroll
        for (int r = 0; r < 8; ++r) {
            float4 w = Wp[(size_t)r * 256 + k4];
            acc[r] += a.x * w.x + a.y * w.y + a.z * w.z + a.w * w.w;
        }
    }
    float4 o0 = {acc[0] + bias[row0 + 0], acc[1] + bias[row0 + 1],
                 acc[2] + bias[row0 + 2], acc[3] + bias[row0 + 3]};
    float4 o1 = {acc[4] + bias[row0 + 4], acc[5] + bias[row0 + 5],
                 acc[6] + bias[row0 + 6], acc[7] + bias[row0 + 7]};
    float* o = out + (size_t)lane * V + row0;
    *reinterpret_cast<float4*>(o) = o0;
    *reinterpret_cast<float4*>(o + 4) = o1;
}

__global__ void lstm_elem(const float* __restrict__ g0, const float* __restrict__ g1,
                          const float* __restrict__ g2, const float* __restrict__ g3,
                          const float* __restrict__ b_ih, const float* __restrict__ b_hh,
                          const float* __restrict__ c_prev, float* __restrict__ h_out,
                          float* __restrict__ c_out, float* __restrict__ hT) {
    int idx = blockIdx.x * 256 + threadIdx.x;   // 0..65535
    int b = idx & 63, k = idx >> 6;             // b fastest -> coalesced on g*
    size_t i0 = (size_t)(0 * 1024 + k) * 64 + b;
    size_t i1 = (size_t)(1 * 1024 + k) * 64 + b;
    size_t i2 = (size_t)(2 * 1024 + k) * 64 + b;
    size_t i3 = (size_t)(3 * 1024 + k) * 64 + b;
    float gi = g0[i0] + g1[i0] + g2[i0] + g3[i0] + b_ih[k] + b_hh[k];
    float gf = g0[i1] + g1[i1] + g2[i1] + g3[i1] + b_ih[1024 + k] + b_hh[1024 + k];
    float gg = g0[i2] + g1[i2] + g2[i2] + g3[i2] + b_ih[2048 + k] + b_hh[2048 + k];
    float go = g0[i3] + g1[i3] + g2[i3] + g3[i3] + b_ih[3072 + k] + b_hh[3072 + k];
    float i_ = 1.f / (1.f + expf(-gi));
    float f_ = 1.f / (1.f + expf(-gf));
    float g_ = tanhf(gg);
    float o_ = 1.f / (1.f + expf(-go));
    float c = f_ * c_prev[b * 1024 + k] + i_ * g_;
    float h = o_ * tanhf(c);
    c_out[b * 1024 + k] = c;
    h_out[b * 1024 + k] = h;
    hT[(k >> 2) * 256 + b * 4 + (k & 3)] = h;
}

// log-softmax over V per row, 4 chunks per row
__global__ void lse_partial(const float* __restrict__ logits, float* __restrict__ pm,
                            float* __restrict__ ps) {
    int bi = blockIdx.x;   // 0..255
    int b = bi >> 2, c = bi & 3;
    int tid = threadIdx.x;
    const float* row = logits + (size_t)b * V + c * 8192;
    int lim = V - c * 8192;
    if (lim > 8192) lim = 8192;
    float m = -1e30f, s = 0.f;
    for (int i = 0; i < 32; ++i) {
        int v = i * 256 + tid;
        if (v < lim) {
            float x = row[v];
            if (x > m) { s = s * expf(m - x) + 1.f; m = x; }
            else s += expf(x - m);
        }
    }
#pragma unroll
    for (int off = 32; off; off >>= 1) {
        float m2 = __shfl_xor(m, off);
        float s2 = __shfl_xor(s, off);
        float mn = fmaxf(m, m2);
        s = s * expf(m - mn) + s2 * expf(m2 - mn);
        m = mn;
    }
    __shared__ float mred[4], sred[4];
    int wid = tid >> 6, lane = tid & 63;
    if (lane == 0) { mred[wid] = m; sred[wid] = s; }
    __syncthreads();
    if (tid == 0) {
        float M = mred[0], S = sred[0];
        for (int i = 1; i < 4; ++i) {
            float mn = fmaxf(M, mred[i]);
            S = S * expf(M - mn) + sred[i] * expf(mred[i] - mn);
            M = mn;
        }
        pm[bi] = M;
        ps[bi] = S;
    }
}

__global__ void lse_final(const float* __restrict__ pm, const float* __restrict__ ps,
                          float* __restrict__ lse) {
    int b = threadIdx.x;   // 64
    float M = pm[b * 4], S = ps[b * 4];
    for (int i = 1; i < 4; ++i) {
        float m2 = pm[b * 4 + i];
        float mn = fmaxf(M, m2);
        S = S * expf(M - mn) + ps[b * 4 + i] * expf(m2 - mn);
        M = mn;
    }
    lse[b] = M + logf(S);
}

__global__ void lse_sub(float4* __restrict__ logits4, const float* __restrict__ lse) {
    int b = blockIdx.y;
    int v4 = blockIdx.x * 256 + threadIdx.x;   // 0..8191, guard at 8000
    if (v4 < 8000) {
        float l = lse[b];
        float4 x = logits4[(size_t)b * 8000 + v4];
        x.x -= l; x.y -= l; x.z -= l; x.w -= l;
        logits4[(size_t)b * 8000 + v4] = x;
    }
}

extern "C" void kernel_launch(void* const* d_in, const int* in_sizes, int n_in,
                              void* d_out, int out_size, void* d_ws, size_t ws_size,
                              hipStream_t stream) {
    const int*   tok   = (const int*)d_in[0];
    const float* h0    = (const float*)d_in[1];
    const float* c0    = (const float*)d_in[2];
    const float* enc   = (const float*)d_in[3];
    const float* emb   = (const float*)d_in[4];
    const float* attnW = (const float*)d_in[5];
    // d_in[6] attn_b: constant over t -> cancels in softmax
    const float* attnv = (const float*)d_in[7];
    const float* w_ih0 = (const float*)d_in[8];
    const float* w_hh0 = (const float*)d_in[9];
    const float* b_ih0 = (const float*)d_in[10];
    const float* b_hh0 = (const float*)d_in[11];
    const float* w_ih1 = (const float*)d_in[12];
    const float* w_hh1 = (const float*)d_in[13];
    const float* b_ih1 = (const float*)d_in[14];
    const float* b_hh1 = (const float*)d_in[15];
    const float* out_W = (const float*)d_in[16];
    const float* out_b = (const float*)d_in[17];
    float* out = (float*)d_out;
    float* ws = (float*)d_ws;

    // ws layout (floats)
    float* u2     = ws + 0;        // 1024
    float* u2p    = ws + 1024;     // 32768
    float* scores = ws + 33792;    // 32768
    float* attn   = ws + 66560;    // 32768
    float* xT     = ws + 99328;    // 131072  [2048/4][64][4]
    float* h0T    = ws + 230400;   // 131072  two layers
    float* h1T    = ws + 361472;   // 65536
    float* h2T    = ws + 427008;   // 65536
    float* pm     = ws + 492544;   // 256
    float* ps     = ws + 492800;   // 256
    float* lsebuf = ws + 493056;   // 64

    // outputs
    float* out_logits = out;                 // [64][32000]
    float* out_h1 = out + 2048000;
    float* out_h2 = out + 2113536;
    float* out_c1 = out + 2179072;
    float* out_c2 = out + 2244608;
    float* out_attn = out + 2310144;         // [64][1][512]

    // scratch inside the logits region of d_out (overwritten later by gemm_logits):
    float* part = out;                       // 16*16384 float4 = 1,048,576 floats
    float* gA0 = out;                        // 262144 each
    float* gA1 = out + 262144;
    float* gB0 = out + 524288;
    float* gB1 = out + 786432;

    u2_partial<<<32, 256, 0, stream>>>((const float4*)attnW, attnv, (float4*)u2p);
    u2_reduce<<<1, 256, 0, stream>>>((const float4*)u2p, (float4*)u2);
    scores_kernel<<<8192, 256, 0, stream>>>((const float4*)enc, (const float4*)u2, scores);
    softmax_kernel<<<64, 256, 0, stream>>>(scores, attn, out_attn);
    ctx_partial<<<dim3(64, 16), 256, 0, stream>>>(attn, (const float4*)enc, (float4*)part);
    ctx_reduce<<<64, 256, 0, stream>>>((const float4*)part, (float4*)xT);
    embT_kernel<<<256, 256, 0, stream>>>(tok, emb, xT + 65536);
    h0T_kernel<<<512, 256, 0, stream>>>(h0, h0T);

    // layer 0: gates = xT(K=2048).w_ih0^T + h0T[0](K=1024).w_hh0^T  (K-split x2 each)
    {
        GJob j0 = {(const float4*)xT, (const float4*)w_ih0, gA0, 512, 0, 256};
        GJob j1 = {(const float4*)xT, (const float4*)w_ih0, gA1, 512, 256, 256};
        GJob j2 = {(const float4*)h0T, (const float4*)w_hh0, gB0, 256, 0, 128};
        GJob j3 = {(const float4*)h0T, (const float4*)w_hh0, gB1, 256, 128, 128};
        gemm_gates<<<dim3(128, 4), 256, 0, stream>>>(j0, j1, j2, j3);
    }
    lstm_elem<<<256, 256, 0, stream>>>(gA0, gA1, gB0, gB1, b_ih0, b_hh0, c0,
                                       out_h1, out_c1, h1T);

    // layer 1
    {
        GJob j0 = {(const float4*)h1T, (const float4*)w_ih1, gA0, 256, 0, 128};
        GJob j1 = {(const float4*)h1T, (const float4*)w_ih1, gA1, 256, 128, 128};
        GJob j2 = {(const float4*)(h0T + 65536), (const float4*)w_hh1, gB0, 256, 0, 128};
        GJob j3 = {(const float4*)(h0T + 65536), (const float4*)w_hh1, gB1, 256, 128, 128};
        gemm_gates<<<dim3(128, 4), 256, 0, stream>>>(j0, j1, j2, j3);
    }
    lstm_elem<<<256, 256, 0, stream>>>(gA0, gA1, gB0, gB1, b_ih1, b_hh1, c0 + 65536,
                                       out_h2, out_c2, h2T);

    // logits = h2 . out_W^T + out_b  -> [64][32000] (overwrites scratch region)
    gemm_logits<<<1000, 256, 0, stream>>>((const float4*)h2T, (const float4*)out_W,
                                          out_b, out_logits);

    lse_partial<<<256, 256, 0, stream>>>(out_logits, pm, ps);
    lse_final<<<1, 64, 0, stream>>>(pm, ps, lsebuf);
    lse_sub<<<dim3(32, 64), 256, 0, stream>>>((float4*)out_logits, lsebuf);
}

// Round 6
// 391.586 us; speedup vs baseline: 1.5507x; 1.2566x over previous
//
#include <hip/hip_runtime.h>

#define V 32000
#define E 1024
#define H 1024
#define B 64
#define T 512

// ---------- u2[k] = sum_h v[h] * W[h, H+k]  (32 h-chunk partials) ----------
__global__ void u2_partial(const float4* __restrict__ W4, const float* __restrict__ v,
                           float4* __restrict__ u2p) {
    int hc = blockIdx.x;           // 0..31
    int k4 = threadIdx.x;          // 0..255
    float4 acc = {0.f, 0.f, 0.f, 0.f};
#pragma unroll 4
    for (int i = 0; i < 32; ++i) {
        int h = hc * 32 + i;
        float vv = v[h];
        float4 w = W4[(size_t)h * 512 + 256 + k4];   // cols 1024..2047
        acc.x += vv * w.x; acc.y += vv * w.y; acc.z += vv * w.z; acc.w += vv * w.w;
    }
    u2p[hc * 256 + k4] = acc;
}

__global__ void u2_reduce(const float4* __restrict__ u2p, float4* __restrict__ u2) {
    int k4 = threadIdx.x;          // 0..255
    float4 acc = {0.f, 0.f, 0.f, 0.f};
#pragma unroll
    for (int hc = 0; hc < 32; ++hc) {
        float4 p = u2p[hc * 256 + k4];
        acc.x += p.x; acc.y += p.y; acc.z += p.z; acc.w += p.w;
    }
    u2[k4] = acc;
}

// scores[b,t] = enc[t,b,:] . u2  (per-b constant part cancels in softmax)
__global__ void scores_kernel(const float4* __restrict__ enc, const float4* __restrict__ u2,
                              float* __restrict__ scores) {
    int wid = (blockIdx.x * blockDim.x + threadIdx.x) >> 6;
    int lane = threadIdx.x & 63;
    int b = wid >> 9;
    int t = wid & 511;
    const float4* p = enc + (size_t)(t * B + b) * (H / 4);
    float acc = 0.f;
#pragma unroll
    for (int i = 0; i < 4; ++i) {
        float4 a = p[lane + 64 * i];
        float4 u = u2[lane + 64 * i];
        acc += a.x * u.x + a.y * u.y + a.z * u.z + a.w * u.w;
    }
#pragma unroll
    for (int off = 32; off; off >>= 1) acc += __shfl_xor(acc, off);
    if (lane == 0) scores[b * T + t] = acc;
}

__global__ void softmax_kernel(const float* __restrict__ scores, float* __restrict__ attn_ws,
                               float* __restrict__ attn_out) {
    int b = blockIdx.x;
    int tid = threadIdx.x;  // 256
    int wid = tid >> 6, lane = tid & 63;
    float s0 = scores[b * T + tid];
    float s1 = scores[b * T + tid + 256];
    float m = fmaxf(s0, s1);
    __shared__ float red[4], red2[4];
#pragma unroll
    for (int off = 32; off; off >>= 1) m = fmaxf(m, __shfl_xor(m, off));
    if (lane == 0) red[wid] = m;
    __syncthreads();
    float mb = fmaxf(fmaxf(red[0], red[1]), fmaxf(red[2], red[3]));
    float e0 = expf(s0 - mb), e1 = expf(s1 - mb);
    float s = e0 + e1;
#pragma unroll
    for (int off = 32; off; off >>= 1) s += __shfl_xor(s, off);
    if (lane == 0) red2[wid] = s;
    __syncthreads();
    float inv = 1.f / (red2[0] + red2[1] + red2[2] + red2[3]);
    attn_ws[b * T + tid] = e0 * inv;
    attn_ws[b * T + tid + 256] = e1 * inv;
    attn_out[b * T + tid] = e0 * inv;
    attn_out[b * T + tid + 256] = e1 * inv;
}

// context partials, written directly in xT ([h/4][b][4]) layout per t-chunk
__global__ void ctx_partial(const float* __restrict__ attn, const float4* __restrict__ enc4,
                            float4* __restrict__ part) {
    int b = blockIdx.x;      // 0..63
    int tc = blockIdx.y;     // 0..15
    int h4 = threadIdx.x;    // 0..255
    float4 acc = {0.f, 0.f, 0.f, 0.f};
#pragma unroll 4
    for (int t = 0; t < 32; ++t) {
        int tt = tc * 32 + t;
        float w = attn[b * T + tt];
        float4 e = enc4[((size_t)tt * B + b) * 256 + h4];
        acc.x += w * e.x; acc.y += w * e.y; acc.z += w * e.z; acc.w += w * e.w;
    }
    part[(size_t)tc * 16384 + h4 * 64 + b] = acc;
}

__global__ void ctx_reduce(const float4* __restrict__ part, float4* __restrict__ xT4) {
    int idx = blockIdx.x * 256 + threadIdx.x;   // 0..16383
    float4 acc = {0.f, 0.f, 0.f, 0.f};
#pragma unroll
    for (int tc = 0; tc < 16; ++tc) {
        float4 p = part[tc * 16384 + idx];
        acc.x += p.x; acc.y += p.y; acc.z += p.z; acc.w += p.w;
    }
    xT4[idx] = acc;
}

__global__ void embT_kernel(const int* __restrict__ tok, const float* __restrict__ emb,
                            float* __restrict__ xT_hi) {
    int idx = blockIdx.x * 256 + threadIdx.x;   // 0..65535
    int e = ((idx >> 8) << 2) | (idx & 3);
    int b = (idx >> 2) & 63;
    xT_hi[idx] = emb[(size_t)tok[b] * E + e];
}

__global__ void h0T_kernel(const float* __restrict__ h0, float* __restrict__ h0T) {
    int idx = blockIdx.x * 256 + threadIdx.x;   // 0..131071 (both layers)
    int l = idx >> 16;
    int r = idx & 65535;
    int k = ((r >> 8) << 2) | (r & 3);
    int b = (r >> 2) & 63;
    h0T[idx] = h0[l * 65536 + b * 1024 + k];
}

// ---------- LDS-staged GEMM: W tiles through the VECTOR path ----------
// Block: 256 thr / 4 waves, 32 output rows (8/wave). k-chunk = 64 floats.
// W staged per-lane coalesced -> LDS; compute reads W via broadcast ds_read_b128
// (prevents the compiler's scalar-load conversion that throttled round 5).
struct GJob {
    const float4* A;    // [K/4][64] float4
    const float4* W4;   // row-major, ldw4 float4 per row
    float* out;         // gates: [rows][64] partial; logits: [64][ldo]
    const float* bias;  // logits only
    int ldw4;           // K/4 of full W row
    int k4_off;
    int k4_len;         // multiple of 16
    int ldo;            // logits only
};

template <bool OUT_BT>
__global__ __launch_bounds__(256) void gemm_lds(GJob j0, GJob j1, GJob j2, GJob j3) {
    GJob job;
    if (blockIdx.y == 0) job = j0;
    else if (blockIdx.y == 1) job = j1;
    else if (blockIdx.y == 2) job = j2;
    else job = j3;
    int lane = threadIdx.x & 63;
    int wid = __builtin_amdgcn_readfirstlane(threadIdx.x >> 6);
    int row0 = blockIdx.x * 32;        // block's first output row
    int rw = wid * 8;                  // wave's first row within tile
    __shared__ float Wt[32][64];       // 8 KB
    __shared__ float4 At[16][64];      // 16 KB
    float acc[8] = {0.f, 0.f, 0.f, 0.f, 0.f, 0.f, 0.f, 0.f};
    int nchunks = job.k4_len >> 4;
    for (int kc = 0; kc < nchunks; ++kc) {
        int kbase = job.k4_off + kc * 16;
        __syncthreads();
#pragma unroll
        for (int i = 0; i < 2; ++i) {   // W: 512 float4 / 256 thr
            int idx = threadIdx.x + i * 256;
            int row = idx >> 4, kp = idx & 15;
            *reinterpret_cast<float4*>(&Wt[row][kp * 4]) =
                job.W4[(size_t)(row0 + row) * job.ldw4 + kbase + kp];
        }
#pragma unroll
        for (int i = 0; i < 4; ++i) {   // A: 1024 float4 / 256 thr
            int idx = threadIdx.x + i * 256;
            int k4 = idx >> 6, b = idx & 63;
            At[k4][b] = job.A[(size_t)(kbase + k4) * 64 + b];
        }
        __syncthreads();
#pragma unroll
        for (int k4 = 0; k4 < 16; ++k4) {
            float4 a = At[k4][lane];
#pragma unroll
            for (int r = 0; r < 8; ++r) {
                float4 w = *reinterpret_cast<const float4*>(&Wt[rw + r][k4 * 4]);
                acc[r] += a.x * w.x + a.y * w.y + a.z * w.z + a.w * w.w;
            }
        }
    }
    if (OUT_BT) {
#pragma unroll
        for (int r = 0; r < 8; ++r)
            job.out[(size_t)(row0 + rw + r) * 64 + lane] = acc[r];
    } else {
        int j = row0 + rw;
        float4 o0 = {acc[0] + job.bias[j + 0], acc[1] + job.bias[j + 1],
                     acc[2] + job.bias[j + 2], acc[3] + job.bias[j + 3]};
        float4 o1 = {acc[4] + job.bias[j + 4], acc[5] + job.bias[j + 5],
                     acc[6] + job.bias[j + 6], acc[7] + job.bias[j + 7]};
        float* o = job.out + (size_t)lane * job.ldo + j;
        *reinterpret_cast<float4*>(o) = o0;
        *reinterpret_cast<float4*>(o + 4) = o1;
    }
}

__global__ void lstm_elem(const float* __restrict__ g0, const float* __restrict__ g1,
                          const float* __restrict__ g2, const float* __restrict__ g3,
                          const float* __restrict__ b_ih, const float* __restrict__ b_hh,
                          const float* __restrict__ c_prev, float* __restrict__ h_out,
                          float* __restrict__ c_out, float* __restrict__ hT) {
    int idx = blockIdx.x * 256 + threadIdx.x;   // 0..65535
    int b = idx & 63, k = idx >> 6;             // b fastest -> coalesced on g*
    size_t i0 = (size_t)(0 * 1024 + k) * 64 + b;
    size_t i1 = (size_t)(1 * 1024 + k) * 64 + b;
    size_t i2 = (size_t)(2 * 1024 + k) * 64 + b;
    size_t i3 = (size_t)(3 * 1024 + k) * 64 + b;
    float gi = g0[i0] + g1[i0] + g2[i0] + g3[i0] + b_ih[k] + b_hh[k];
    float gf = g0[i1] + g1[i1] + g2[i1] + g3[i1] + b_ih[1024 + k] + b_hh[1024 + k];
    float gg = g0[i2] + g1[i2] + g2[i2] + g3[i2] + b_ih[2048 + k] + b_hh[2048 + k];
    float go = g0[i3] + g1[i3] + g2[i3] + g3[i3] + b_ih[3072 + k] + b_hh[3072 + k];
    float i_ = 1.f / (1.f + expf(-gi));
    float f_ = 1.f / (1.f + expf(-gf));
    float g_ = tanhf(gg);
    float o_ = 1.f / (1.f + expf(-go));
    float c = f_ * c_prev[b * 1024 + k] + i_ * g_;
    float h = o_ * tanhf(c);
    c_out[b * 1024 + k] = c;
    h_out[b * 1024 + k] = h;
    hT[(k >> 2) * 256 + b * 4 + (k & 3)] = h;
}

// log-softmax over V per row, 16 chunks per row for occupancy
__global__ void lse_partial(const float* __restrict__ logits, float* __restrict__ pm,
                            float* __restrict__ ps) {
    int bi = blockIdx.x;   // 0..1023
    int b = bi >> 4, c = bi & 15;
    int tid = threadIdx.x;
    const float* row = logits + (size_t)b * V + c * 2000;
    float m = -1e30f, s = 0.f;
#pragma unroll
    for (int i = 0; i < 8; ++i) {
        int v = i * 256 + tid;
        if (v < 2000) {
            float x = row[v];
            if (x > m) { s = s * expf(m - x) + 1.f; m = x; }
            else s += expf(x - m);
        }
    }
#pragma unroll
    for (int off = 32; off; off >>= 1) {
        float m2 = __shfl_xor(m, off);
        float s2 = __shfl_xor(s, off);
        float mn = fmaxf(m, m2);
        s = s * expf(m - mn) + s2 * expf(m2 - mn);
        m = mn;
    }
    __shared__ float mred[4], sred[4];
    int wid = tid >> 6, lane = tid & 63;
    if (lane == 0) { mred[wid] = m; sred[wid] = s; }
    __syncthreads();
    if (tid == 0) {
        float M = mred[0], S = sred[0];
        for (int i = 1; i < 4; ++i) {
            float mn = fmaxf(M, mred[i]);
            S = S * expf(M - mn) + sred[i] * expf(mred[i] - mn);
            M = mn;
        }
        pm[bi] = M;
        ps[bi] = S;
    }
}

__global__ void lse_final(const float* __restrict__ pm, const float* __restrict__ ps,
                          float* __restrict__ lse) {
    int b = threadIdx.x;   // 64
    float M = pm[b * 16], S = ps[b * 16];
    for (int i = 1; i < 16; ++i) {
        float m2 = pm[b * 16 + i];
        float mn = fmaxf(M, m2);
        S = S * expf(M - mn) + ps[b * 16 + i] * expf(m2 - mn);
        M = mn;
    }
    lse[b] = M + logf(S);
}

__global__ void lse_sub(float4* __restrict__ logits4, const float* __restrict__ lse) {
    int b = blockIdx.y;
    int v4 = blockIdx.x * 256 + threadIdx.x;   // 0..8191, guard at 8000
    if (v4 < 8000) {
        float l = lse[b];
        float4 x = logits4[(size_t)b * 8000 + v4];
        x.x -= l; x.y -= l; x.z -= l; x.w -= l;
        logits4[(size_t)b * 8000 + v4] = x;
    }
}

extern "C" void kernel_launch(void* const* d_in, const int* in_sizes, int n_in,
                              void* d_out, int out_size, void* d_ws, size_t ws_size,
                              hipStream_t stream) {
    const int*   tok   = (const int*)d_in[0];
    const float* h0    = (const float*)d_in[1];
    const float* c0    = (const float*)d_in[2];
    const float* enc   = (const float*)d_in[3];
    const float* emb   = (const float*)d_in[4];
    const float* attnW = (const float*)d_in[5];
    // d_in[6] attn_b: constant over t -> cancels in softmax
    const float* attnv = (const float*)d_in[7];
    const float* w_ih0 = (const float*)d_in[8];
    const float* w_hh0 = (const float*)d_in[9];
    const float* b_ih0 = (const float*)d_in[10];
    const float* b_hh0 = (const float*)d_in[11];
    const float* w_ih1 = (const float*)d_in[12];
    const float* w_hh1 = (const float*)d_in[13];
    const float* b_ih1 = (const float*)d_in[14];
    const float* b_hh1 = (const float*)d_in[15];
    const float* out_W = (const float*)d_in[16];
    const float* out_b = (const float*)d_in[17];
    float* out = (float*)d_out;
    float* ws = (float*)d_ws;

    // ws layout (floats)
    float* u2     = ws + 0;        // 1024
    float* u2p    = ws + 1024;     // 32768
    float* scores = ws + 33792;    // 32768
    float* attn   = ws + 66560;    // 32768
    float* xT     = ws + 99328;    // 131072  [2048/4][64][4]
    float* h0T    = ws + 230400;   // 131072  two layers
    float* h1T    = ws + 361472;   // 65536
    float* h2T    = ws + 427008;   // 65536
    float* pm     = ws + 492544;   // 1024
    float* ps     = ws + 493568;   // 1024
    float* lsebuf = ws + 494592;   // 64

    // outputs
    float* out_logits = out;                 // [64][32000]
    float* out_h1 = out + 2048000;
    float* out_h2 = out + 2113536;
    float* out_c1 = out + 2179072;
    float* out_c2 = out + 2244608;
    float* out_attn = out + 2310144;         // [64][1][512]

    // scratch inside the logits region of d_out (overwritten later by gemm_lds<false>):
    float* part = out;                       // 16*16384 float4 = 1,048,576 floats
    float* gA0 = out;                        // 262144 each
    float* gA1 = out + 262144;
    float* gB0 = out + 524288;
    float* gB1 = out + 786432;

    u2_partial<<<32, 256, 0, stream>>>((const float4*)attnW, attnv, (float4*)u2p);
    u2_reduce<<<1, 256, 0, stream>>>((const float4*)u2p, (float4*)u2);
    scores_kernel<<<8192, 256, 0, stream>>>((const float4*)enc, (const float4*)u2, scores);
    softmax_kernel<<<64, 256, 0, stream>>>(scores, attn, out_attn);
    ctx_partial<<<dim3(64, 16), 256, 0, stream>>>(attn, (const float4*)enc, (float4*)part);
    ctx_reduce<<<64, 256, 0, stream>>>((const float4*)part, (float4*)xT);
    embT_kernel<<<256, 256, 0, stream>>>(tok, emb, xT + 65536);
    h0T_kernel<<<512, 256, 0, stream>>>(h0, h0T);

    // layer 0: gates = xT(K=2048).w_ih0^T + h0T[0](K=1024).w_hh0^T  (K-split x2 each)
    {
        GJob j0 = {(const float4*)xT, (const float4*)w_ih0, gA0, nullptr, 512, 0, 256, 0};
        GJob j1 = {(const float4*)xT, (const float4*)w_ih0, gA1, nullptr, 512, 256, 256, 0};
        GJob j2 = {(const float4*)h0T, (const float4*)w_hh0, gB0, nullptr, 256, 0, 128, 0};
        GJob j3 = {(const float4*)h0T, (const float4*)w_hh0, gB1, nullptr, 256, 128, 128, 0};
        gemm_lds<true><<<dim3(128, 4), 256, 0, stream>>>(j0, j1, j2, j3);
    }
    lstm_elem<<<256, 256, 0, stream>>>(gA0, gA1, gB0, gB1, b_ih0, b_hh0, c0,
                                       out_h1, out_c1, h1T);

    // layer 1
    {
        GJob j0 = {(const float4*)h1T, (const float4*)w_ih1, gA0, nullptr, 256, 0, 128, 0};
        GJob j1 = {(const float4*)h1T, (const float4*)w_ih1, gA1, nullptr, 256, 128, 128, 0};
        GJob j2 = {(const float4*)(h0T + 65536), (const float4*)w_hh1, gB0, nullptr, 256, 0, 128, 0};
        GJob j3 = {(const float4*)(h0T + 65536), (const float4*)w_hh1, gB1, nullptr, 256, 128, 128, 0};
        gemm_lds<true><<<dim3(128, 4), 256, 0, stream>>>(j0, j1, j2, j3);
    }
    lstm_elem<<<256, 256, 0, stream>>>(gA0, gA1, gB0, gB1, b_ih1, b_hh1, c0 + 65536,
                                       out_h2, out_c2, h2T);

    // logits = h2 . out_W^T + out_b  -> [64][32000] (overwrites scratch region)
    {
        GJob j0 = {(const float4*)h2T, (const float4*)out_W, out_logits, out_b, 256, 0, 256, V};
        gemm_lds<false><<<dim3(1000, 1), 256, 0, stream>>>(j0, j0, j0, j0);
    }

    lse_partial<<<1024, 256, 0, stream>>>(out_logits, pm, ps);
    lse_final<<<1, 64, 0, stream>>>(pm, ps, lsebuf);
    lse_sub<<<dim3(32, 64), 256, 0, stream>>>((float4*)out_logits, lsebuf);
}